// Round 1
// baseline (176.853 us; speedup 1.0000x reference)
//
#include <hip/hip_runtime.h>

typedef unsigned short u16;
typedef unsigned int u32;
typedef short bf16x8 __attribute__((ext_vector_type(8)));
typedef float f32x4 __attribute__((ext_vector_type(4)));

#define MFMA(a, b, c) __builtin_amdgcn_mfma_f32_16x16x32_bf16((a), (b), (c), 0, 0, 0)

#define BB 2
#define SS 2048
#define DD 768
#define HH 12
#define MROWS (BB * SS) /* 4096 */

__device__ __forceinline__ u16 f2bf(float f) {
  u32 u = __float_as_uint(f);
  u += 0x7FFFu + ((u >> 16) & 1u);  // round-to-nearest-even
  return (u16)(u >> 16);
}

// ---------------- convert x (fp32 -> bf16) ----------------
__global__ __launch_bounds__(256) void k_convert(const float* __restrict__ in,
                                                 u16* __restrict__ out, int n) {
  int i = (blockIdx.x * 256 + threadIdx.x) * 4;
  if (i < n) {
    float4 v = *(const float4*)(in + i);
    ushort4 o;
    o.x = f2bf(v.x); o.y = f2bf(v.y); o.z = f2bf(v.z); o.w = f2bf(v.w);
    *(ushort4*)(out + i) = o;
  }
}

// ------- transpose+convert the 4 weight matrices: out[z][n][k] = W_z[k][n] -------
__global__ __launch_bounds__(256) void k_transpose_w(
    const float* __restrict__ Wq, const float* __restrict__ Wk,
    const float* __restrict__ Wv, const float* __restrict__ Wo,
    u16* __restrict__ out) {
  const float* W = (blockIdx.z == 0) ? Wq : (blockIdx.z == 1) ? Wk
                   : (blockIdx.z == 2) ? Wv : Wo;
  u16* o = out + (size_t)blockIdx.z * DD * DD;
  __shared__ float tile[32][33];
  int kt = blockIdx.x * 32, nt = blockIdx.y * 32;
  int tx = threadIdx.x & 31, ty = threadIdx.x >> 5;
#pragma unroll
  for (int r = 0; r < 4; r++) {
    int row = ty + r * 8;
    tile[row][tx] = W[(size_t)(kt + row) * DD + nt + tx];
  }
  __syncthreads();
#pragma unroll
  for (int r = 0; r < 4; r++) {
    int row = ty + r * 8;
    o[(size_t)(nt + row) * DD + kt + tx] = f2bf(tile[tx][row]);
  }
}

// ---------------- 128x128-tile bf16 MFMA GEMM: C = A @ Bt^T + bias ----------------
// A: [M x 768] bf16 row-major. Bt: [768 x 768] bf16 with Bt[n][k] = B[k][n].
template <bool OUT_BF16>
__device__ __forceinline__ void gemm128(const u16* __restrict__ A,
                                        const u16* __restrict__ Bt,
                                        const float* __restrict__ bias,
                                        void* __restrict__ Cout, int m0, int n0) {
  __shared__ __align__(16) u16 Al[128 * 40];  // [m][k], pad 40 (2-way-friendly)
  __shared__ __align__(16) u16 Bl[128 * 40];  // [n][k]
  int t = threadIdx.x;
  int lane = t & 63, w = t >> 6;
  int wm = (w >> 1) * 64, wn = (w & 1) * 64;
  int l15 = lane & 15, l4 = lane >> 4;
  f32x4 acc[4][4];
#pragma unroll
  for (int i = 0; i < 4; i++)
#pragma unroll
    for (int j = 0; j < 4; j++) acc[i][j] = (f32x4){0.f, 0.f, 0.f, 0.f};

  for (int k0 = 0; k0 < DD; k0 += 32) {
#pragma unroll
    for (int rep = 0; rep < 2; rep++) {
      int idx = rep * 256 + t;
      int row = idx >> 2, k8 = (idx & 3) << 3;
      *(uint4*)(&Al[row * 40 + k8]) =
          *(const uint4*)(A + (size_t)(m0 + row) * DD + k0 + k8);
      *(uint4*)(&Bl[row * 40 + k8]) =
          *(const uint4*)(Bt + (size_t)(n0 + row) * DD + k0 + k8);
    }
    __syncthreads();
    bf16x8 af[4], bfr[4];
#pragma unroll
    for (int mb = 0; mb < 4; mb++)
      af[mb] = *(const bf16x8*)(&Al[(wm + mb * 16 + l15) * 40 + l4 * 8]);
#pragma unroll
    for (int nb = 0; nb < 4; nb++)
      bfr[nb] = *(const bf16x8*)(&Bl[(wn + nb * 16 + l15) * 40 + l4 * 8]);
#pragma unroll
    for (int mb = 0; mb < 4; mb++)
#pragma unroll
      for (int nb = 0; nb < 4; nb++)
        acc[mb][nb] = MFMA(af[mb], bfr[nb], acc[mb][nb]);
    __syncthreads();
  }
  // epilogue: C/D layout col=lane&15, row=(lane>>4)*4+reg  [verified m89/m91]
#pragma unroll
  for (int nb = 0; nb < 4; nb++) {
    int col = n0 + wn + nb * 16 + l15;
    float bs = bias[col];
#pragma unroll
    for (int mb = 0; mb < 4; mb++) {
#pragma unroll
      for (int r = 0; r < 4; r++) {
        int row = m0 + wm + mb * 16 + l4 * 4 + r;
        float vv = acc[mb][nb][r] + bs;
        if (OUT_BF16)
          ((u16*)Cout)[(size_t)row * DD + col] = f2bf(vv);
        else
          ((float*)Cout)[(size_t)row * DD + col] = vv;
      }
    }
  }
}

__global__ __launch_bounds__(256) void k_gemm_qkv(
    const u16* __restrict__ xb, const u16* __restrict__ Wt,
    const float* __restrict__ bq, const float* __restrict__ bk,
    const float* __restrict__ bv, u16* __restrict__ qkv) {
  int z = blockIdx.z;
  const u16* Bt = Wt + (size_t)z * DD * DD;
  const float* bias = (z == 0) ? bq : (z == 1) ? bk : bv;
  u16* out = qkv + (size_t)z * MROWS * DD;
  gemm128<true>(xb, Bt, bias, out, blockIdx.x * 128, blockIdx.y * 128);
}

__global__ __launch_bounds__(256) void k_gemm_out(
    const u16* __restrict__ ctx, const u16* __restrict__ Wot,
    const float* __restrict__ bo, float* __restrict__ out) {
  gemm128<false>(ctx, Wot, bo, out, blockIdx.x * 128, blockIdx.y * 128);
}

// ---------------- flash attention (causal) ----------------
// grid: (S/64, B*H). 256 threads = 4 waves; wave w owns 16 Q-rows.
__global__ __launch_bounds__(256) void k_attn(const u16* __restrict__ qb,
                                              const u16* __restrict__ kb,
                                              const u16* __restrict__ vb,
                                              u16* __restrict__ ctx) {
  __shared__ __align__(16) u16 Kl[64 * 72];      // K tile [j][d], pad 72
  __shared__ __align__(16) u16 Vt[64 * 72];      // V tile transposed [d][j]
  __shared__ __align__(16) u16 Pl[4 * 16 * 72];  // per-wave P [q][j]
  int qt = blockIdx.x;
  int bh = blockIdx.y;
  int b = bh / HH, h = bh % HH;
  int t = threadIdx.x, w = t >> 6, lane = t & 63;
  int l15 = lane & 15, l4 = lane >> 4;
  size_t rowbase = (size_t)b * SS;
  int hcol = h * 64;

  // Q fragments stay in registers for the whole block
  int qrow = qt * 64 + w * 16 + l15;
  const u16* qptr = qb + (rowbase + qrow) * DD + hcol;
  bf16x8 qf0 = *(const bf16x8*)(qptr + l4 * 8);
  bf16x8 qf1 = *(const bf16x8*)(qptr + 32 + l4 * 8);

  float m_r[4], l_r[4];
  f32x4 o[4];
#pragma unroll
  for (int r = 0; r < 4; r++) { m_r[r] = -3e38f; l_r[r] = 0.f; }
#pragma unroll
  for (int nd = 0; nd < 4; nd++) o[nd] = (f32x4){0.f, 0.f, 0.f, 0.f};

  u16* Pw = Pl + w * 16 * 72;
  int jj = t & 63, dblk = (t >> 6) * 8;
  const f32x4 z4 = {0.f, 0.f, 0.f, 0.f};

  for (int kt = 0; kt <= qt; kt++) {
    __syncthreads();  // protect LDS from previous iteration's readers
    const u16* krowp = kb + (rowbase + kt * 64 + jj) * DD + hcol;
    const u16* vrowp = vb + (rowbase + kt * 64 + jj) * DD + hcol;
#pragma unroll
    for (int rep = 0; rep < 2; rep++) {
      int d8 = dblk + rep * 32;
      *(uint4*)(&Kl[jj * 72 + d8]) = *(const uint4*)(krowp + d8);
      uint4 vv = *(const uint4*)(vrowp + d8);
      u16 el[8];
      *(uint4*)el = vv;
#pragma unroll
      for (int i = 0; i < 8; i++) Vt[(d8 + i) * 72 + jj] = el[i];
    }
    __syncthreads();

    // S = Q K^T  (A=Q row=lane&15; B=K^T col=j=lane&15, k=d contiguous)
    f32x4 sacc[4];
#pragma unroll
    for (int nb = 0; nb < 4; nb++) {
      bf16x8 kf0 = *(const bf16x8*)(&Kl[(nb * 16 + l15) * 72 + l4 * 8]);
      bf16x8 kf1 = *(const bf16x8*)(&Kl[(nb * 16 + l15) * 72 + 32 + l4 * 8]);
      sacc[nb] = MFMA(qf0, kf0, z4);
      sacc[nb] = MFMA(qf1, kf1, sacc[nb]);
    }
    float s[4][4];
#pragma unroll
    for (int nb = 0; nb < 4; nb++)
#pragma unroll
      for (int r = 0; r < 4; r++) s[nb][r] = sacc[nb][r] * 0.125f;
    if (kt == qt) {  // diagonal tile: causal mask (tile-local indices valid)
#pragma unroll
      for (int nb = 0; nb < 4; nb++) {
        int jg = nb * 16 + l15;
#pragma unroll
        for (int r = 0; r < 4; r++) {
          int qg = w * 16 + l4 * 4 + r;
          if (jg > qg) s[nb][r] = -1e30f;
        }
      }
    }
    // online softmax: each q-row lives across 16 lanes (lane&15) x 4 nb
    float alpha[4];
#pragma unroll
    for (int r = 0; r < 4; r++) {
      float mx = fmaxf(fmaxf(s[0][r], s[1][r]), fmaxf(s[2][r], s[3][r]));
      mx = fmaxf(mx, __shfl_xor(mx, 1, 64));
      mx = fmaxf(mx, __shfl_xor(mx, 2, 64));
      mx = fmaxf(mx, __shfl_xor(mx, 4, 64));
      mx = fmaxf(mx, __shfl_xor(mx, 8, 64));
      float mn = fmaxf(m_r[r], mx);
      alpha[r] = __expf(m_r[r] - mn);
      m_r[r] = mn;
      float rs = 0.f;
#pragma unroll
      for (int nb = 0; nb < 4; nb++) {
        float p = __expf(s[nb][r] - mn);
        s[nb][r] = p;
        rs += p;
      }
      rs += __shfl_xor(rs, 1, 64);
      rs += __shfl_xor(rs, 2, 64);
      rs += __shfl_xor(rs, 4, 64);
      rs += __shfl_xor(rs, 8, 64);
      l_r[r] = l_r[r] * alpha[r] + rs;
    }
    // P -> wave-private LDS (bf16), rescale O, then PV
#pragma unroll
    for (int nb = 0; nb < 4; nb++)
#pragma unroll
      for (int r = 0; r < 4; r++)
        Pw[(l4 * 4 + r) * 72 + nb * 16 + l15] = f2bf(s[nb][r]);
#pragma unroll
    for (int nd = 0; nd < 4; nd++)
#pragma unroll
      for (int r = 0; r < 4; r++) o[nd][r] *= alpha[r];
    asm volatile("s_waitcnt lgkmcnt(0)" ::: "memory");  // wave-local P ready
    bf16x8 pa0 = *(const bf16x8*)(&Pw[l15 * 72 + l4 * 8]);
    bf16x8 pa1 = *(const bf16x8*)(&Pw[l15 * 72 + 32 + l4 * 8]);
#pragma unroll
    for (int nd = 0; nd < 4; nd++) {
      bf16x8 vf0 = *(const bf16x8*)(&Vt[(nd * 16 + l15) * 72 + l4 * 8]);
      bf16x8 vf1 = *(const bf16x8*)(&Vt[(nd * 16 + l15) * 72 + 32 + l4 * 8]);
      o[nd] = MFMA(pa0, vf0, o[nd]);
      o[nd] = MFMA(pa1, vf1, o[nd]);
    }
  }
  // writeback ctx (bf16, [B,S,D] layout)
  size_t orow = rowbase + (size_t)qt * 64 + w * 16 + l4 * 4;
#pragma unroll
  for (int nd = 0; nd < 4; nd++)
#pragma unroll
    for (int r = 0; r < 4; r++) {
      float vv = o[nd][r] / l_r[r];
      ctx[(orow + r) * DD + hcol + nd * 16 + l15] = f2bf(vv);
    }
}

extern "C" void kernel_launch(void* const* d_in, const int* in_sizes, int n_in,
                              void* d_out, int out_size, void* d_ws, size_t ws_size,
                              hipStream_t stream) {
  const float* x  = (const float*)d_in[0];
  // d_in[1] = mask (causal, hard-coded in k_attn)
  const float* Wq = (const float*)d_in[2];
  const float* bq = (const float*)d_in[3];
  const float* Wk = (const float*)d_in[4];
  const float* bk = (const float*)d_in[5];
  const float* Wv = (const float*)d_in[6];
  const float* bv = (const float*)d_in[7];
  const float* Wo = (const float*)d_in[8];
  const float* bo = (const float*)d_in[9];
  float* out = (float*)d_out;

  char* ws = (char*)d_ws;
  const size_t XN = (size_t)MROWS * DD;  // 3,145,728
  const size_t WN = (size_t)DD * DD;     // 589,824
  u16* xb  = (u16*)ws;                                 // XN
  u16* Wt  = (u16*)(ws + XN * 2);                      // 4*WN
  u16* qkv = (u16*)(ws + XN * 2 + WN * 8);             // 3*XN
  u16* ctx = (u16*)(ws + XN * 2 + WN * 8 + XN * 6);    // XN

  k_convert<<<dim3((int)(XN / 1024)), 256, 0, stream>>>(x, xb, (int)XN);
  k_transpose_w<<<dim3(24, 24, 4), 256, 0, stream>>>(Wq, Wk, Wv, Wo, Wt);
  k_gemm_qkv<<<dim3(32, 6, 3), 256, 0, stream>>>(xb, Wt, bq, bk, bv, qkv);
  k_attn<<<dim3(32, 24), 256, 0, stream>>>(qkv, qkv + XN, qkv + 2 * XN, ctx);
  k_gemm_out<<<dim3(32, 6), 256, 0, stream>>>(ctx, Wt + 3 * WN, bo, out);
}

// Round 2
// 154.986 us; speedup vs baseline: 1.1411x; 1.1411x over previous
//
#include <hip/hip_runtime.h>

typedef unsigned short u16;
typedef unsigned int u32;
typedef short bf16x8 __attribute__((ext_vector_type(8)));
typedef float f32x4 __attribute__((ext_vector_type(4)));

#define MFMA(a, b, c) __builtin_amdgcn_mfma_f32_16x16x32_bf16((a), (b), (c), 0, 0, 0)

#define BB 2
#define SS 2048
#define DD 768
#define HH 12
#define MROWS (BB * SS) /* 4096 */

__device__ __forceinline__ u16 f2bf(float f) {
  u32 u = __float_as_uint(f);
  u += 0x7FFFu + ((u >> 16) & 1u);  // round-to-nearest-even
  return (u16)(u >> 16);
}

// ---------------- convert x (fp32 -> bf16) ----------------
__global__ __launch_bounds__(256) void k_convert(const float* __restrict__ in,
                                                 u16* __restrict__ out, int n) {
  int i = (blockIdx.x * 256 + threadIdx.x) * 4;
  if (i < n) {
    float4 v = *(const float4*)(in + i);
    ushort4 o;
    o.x = f2bf(v.x); o.y = f2bf(v.y); o.z = f2bf(v.z); o.w = f2bf(v.w);
    *(ushort4*)(out + i) = o;
  }
}

// ------- transpose+convert the 4 weight matrices: out[z][n][k] = W_z[k][n] -------
__global__ __launch_bounds__(256) void k_transpose_w(
    const float* __restrict__ Wq, const float* __restrict__ Wk,
    const float* __restrict__ Wv, const float* __restrict__ Wo,
    u16* __restrict__ out) {
  const float* W = (blockIdx.z == 0) ? Wq : (blockIdx.z == 1) ? Wk
                   : (blockIdx.z == 2) ? Wv : Wo;
  u16* o = out + (size_t)blockIdx.z * DD * DD;
  __shared__ float tile[32][33];
  int kt = blockIdx.x * 32, nt = blockIdx.y * 32;
  int tx = threadIdx.x & 31, ty = threadIdx.x >> 5;
#pragma unroll
  for (int r = 0; r < 4; r++) {
    int row = ty + r * 8;
    tile[row][tx] = W[(size_t)(kt + row) * DD + nt + tx];
  }
  __syncthreads();
#pragma unroll
  for (int r = 0; r < 4; r++) {
    int row = ty + r * 8;
    o[(size_t)(nt + row) * DD + kt + tx] = f2bf(tile[tx][row]);
  }
}

// ---------------- 128x128-tile bf16 MFMA GEMM: C = A @ Bt^T + bias ----------------
// A: [M x 768] bf16 row-major. Bt: [768 x 768] bf16 with Bt[n][k] = B[k][n].
template <bool OUT_BF16>
__device__ __forceinline__ void gemm128(const u16* __restrict__ A,
                                        const u16* __restrict__ Bt,
                                        const float* __restrict__ bias,
                                        void* __restrict__ Cout, int m0, int n0) {
  __shared__ __align__(16) u16 Al[128 * 40];  // [m][k], pad 40
  __shared__ __align__(16) u16 Bl[128 * 40];  // [n][k]
  int t = threadIdx.x;
  int lane = t & 63, w = t >> 6;
  int wm = (w >> 1) * 64, wn = (w & 1) * 64;
  int l15 = lane & 15, l4 = lane >> 4;
  f32x4 acc[4][4];
#pragma unroll
  for (int i = 0; i < 4; i++)
#pragma unroll
    for (int j = 0; j < 4; j++) acc[i][j] = (f32x4){0.f, 0.f, 0.f, 0.f};

  for (int k0 = 0; k0 < DD; k0 += 32) {
#pragma unroll
    for (int rep = 0; rep < 2; rep++) {
      int idx = rep * 256 + t;
      int row = idx >> 2, k8 = (idx & 3) << 3;
      *(uint4*)(&Al[row * 40 + k8]) =
          *(const uint4*)(A + (size_t)(m0 + row) * DD + k0 + k8);
      *(uint4*)(&Bl[row * 40 + k8]) =
          *(const uint4*)(Bt + (size_t)(n0 + row) * DD + k0 + k8);
    }
    __syncthreads();
    bf16x8 af[4], bfr[4];
#pragma unroll
    for (int mb = 0; mb < 4; mb++)
      af[mb] = *(const bf16x8*)(&Al[(wm + mb * 16 + l15) * 40 + l4 * 8]);
#pragma unroll
    for (int nb = 0; nb < 4; nb++)
      bfr[nb] = *(const bf16x8*)(&Bl[(wn + nb * 16 + l15) * 40 + l4 * 8]);
    __builtin_amdgcn_s_setprio(1);
#pragma unroll
    for (int mb = 0; mb < 4; mb++)
#pragma unroll
      for (int nb = 0; nb < 4; nb++)
        acc[mb][nb] = MFMA(af[mb], bfr[nb], acc[mb][nb]);
    __builtin_amdgcn_s_setprio(0);
    __syncthreads();
  }
  // epilogue: C/D layout col=lane&15, row=(lane>>4)*4+reg  [verified m89/m91]
#pragma unroll
  for (int nb = 0; nb < 4; nb++) {
    int col = n0 + wn + nb * 16 + l15;
    float bs = bias[col];
#pragma unroll
    for (int mb = 0; mb < 4; mb++) {
#pragma unroll
      for (int r = 0; r < 4; r++) {
        int row = m0 + wm + mb * 16 + l4 * 4 + r;
        float vv = acc[mb][nb][r] + bs;
        if (OUT_BF16)
          ((u16*)Cout)[(size_t)row * DD + col] = f2bf(vv);
        else
          ((float*)Cout)[(size_t)row * DD + col] = vv;
      }
    }
  }
}

__global__ __launch_bounds__(256) void k_gemm_qkv(
    const u16* __restrict__ xb, const u16* __restrict__ Wt,
    const float* __restrict__ bq, const float* __restrict__ bk,
    const float* __restrict__ bv, u16* __restrict__ qkv) {
  int z = blockIdx.z;
  const u16* Bt = Wt + (size_t)z * DD * DD;
  const float* bias = (z == 0) ? bq : (z == 1) ? bk : bv;
  u16* out = qkv + (size_t)z * MROWS * DD;
  gemm128<true>(xb, Bt, bias, out, blockIdx.x * 128, blockIdx.y * 128);
}

__global__ __launch_bounds__(256) void k_gemm_out(
    const u16* __restrict__ ctx, const u16* __restrict__ Wot,
    const float* __restrict__ bo, float* __restrict__ out) {
  gemm128<false>(ctx, Wot, bo, out, blockIdx.x * 128, blockIdx.y * 128);
}

// ---------------- flash attention (causal) ----------------
// grid: (B*H, S/64). 256 threads = 4 waves; wave w owns 16 Q-rows.
// qt = 31 - blockIdx.y: LPT (longest blocks dispatch first).
// LDS: XOR-swizzled (byte ^= (row&7)<<4), stride 64 u16 = 128B, no pad.
// K/V staging: register prefetch of tile kt+1 overlaps compute of tile kt.
__global__ __launch_bounds__(256) void k_attn(const u16* __restrict__ qb,
                                              const u16* __restrict__ kb,
                                              const u16* __restrict__ vb,
                                              u16* __restrict__ ctx) {
  __shared__ __align__(16) u16 Kl[64 * 64];      // K tile [j][d], swizzled
  __shared__ __align__(16) u16 Vt[64 * 64];      // V tile transposed [d][j], swizzled
  __shared__ __align__(16) u16 Pl[4 * 16 * 64];  // per-wave P [q][j], swizzled
  int qt = (int)gridDim.y - 1 - (int)blockIdx.y;  // descending qt = LPT order
  int bh = blockIdx.x;
  int b = bh / HH, h = bh % HH;
  int t = threadIdx.x, w = t >> 6, lane = t & 63;
  int l15 = lane & 15, l4 = lane >> 4;
  size_t rowbase = (size_t)b * SS;
  int hcol = h * 64;

  // Q fragments stay in registers for the whole block
  int qrow = qt * 64 + w * 16 + l15;
  const u16* qptr = qb + (rowbase + qrow) * DD + hcol;
  bf16x8 qf0 = *(const bf16x8*)(qptr + l4 * 8);
  bf16x8 qf1 = *(const bf16x8*)(qptr + 32 + l4 * 8);

  float m_r[4], l_r[4];
  f32x4 o[4];
#pragma unroll
  for (int r = 0; r < 4; r++) { m_r[r] = -3e38f; l_r[r] = 0.f; }
#pragma unroll
  for (int nd = 0; nd < 4; nd++) o[nd] = (f32x4){0.f, 0.f, 0.f, 0.f};

  char* Kb = (char*)Kl;
  char* Vb = (char*)Vt;
  char* Pb = (char*)(Pl + w * 16 * 64);
  const u16* kbase = kb + rowbase * DD + hcol;
  const u16* vbase = vb + rowbase * DD + hcol;
  // staging geometry: 512 uint4 chunks per tile, 2 per thread
  int srow = t >> 3, sc = t & 7;  // rows 0..31 (+32 on rep 1), 16B chunk
  const f32x4 z4 = {0.f, 0.f, 0.f, 0.f};

  uint4 kr[2], vr[2];
  // prologue: load tile 0
#pragma unroll
  for (int rep = 0; rep < 2; rep++) {
    int row = srow + rep * 32;
    kr[rep] = *(const uint4*)(kbase + (size_t)row * DD + sc * 8);
    vr[rep] = *(const uint4*)(vbase + (size_t)row * DD + sc * 8);
  }

  for (int kt = 0; kt <= qt; kt++) {
    // write staged registers -> LDS (swizzled)
#pragma unroll
    for (int rep = 0; rep < 2; rep++) {
      int row = srow + rep * 32;
      *(uint4*)(Kb + ((row * 128 + sc * 16) ^ ((row & 7) << 4))) = kr[rep];
      u16 el[8];
      *(uint4*)el = vr[rep];
#pragma unroll
      for (int i = 0; i < 8; i++) {
        int d = sc * 8 + i;
        *(u16*)(Vb + ((d * 128 + row * 2) ^ ((d & 7) << 4))) = el[i];
      }
    }
    __syncthreads();
    // issue next tile's global loads early (latency hidden under compute)
    if (kt < qt) {
#pragma unroll
      for (int rep = 0; rep < 2; rep++) {
        int row = (kt + 1) * 64 + srow + rep * 32;
        kr[rep] = *(const uint4*)(kbase + (size_t)row * DD + sc * 8);
        vr[rep] = *(const uint4*)(vbase + (size_t)row * DD + sc * 8);
      }
    }

    // S = Q K^T
    f32x4 sacc[4];
#pragma unroll
    for (int nb = 0; nb < 4; nb++) {
      int row = nb * 16 + l15;
      bf16x8 kf0 = *(const bf16x8*)(Kb + ((row * 128 + l4 * 16) ^ ((row & 7) << 4)));
      bf16x8 kf1 = *(const bf16x8*)(Kb + ((row * 128 + 64 + l4 * 16) ^ ((row & 7) << 4)));
      __builtin_amdgcn_s_setprio(1);
      sacc[nb] = MFMA(qf0, kf0, z4);
      sacc[nb] = MFMA(qf1, kf1, sacc[nb]);
      __builtin_amdgcn_s_setprio(0);
    }
    float s[4][4];
#pragma unroll
    for (int nb = 0; nb < 4; nb++)
#pragma unroll
      for (int r = 0; r < 4; r++) s[nb][r] = sacc[nb][r] * 0.125f;
    if (kt == qt) {  // diagonal tile: causal mask (tile-local indices valid)
#pragma unroll
      for (int nb = 0; nb < 4; nb++) {
        int jg = nb * 16 + l15;
#pragma unroll
        for (int r = 0; r < 4; r++) {
          int qg = w * 16 + l4 * 4 + r;
          if (jg > qg) s[nb][r] = -1e30f;
        }
      }
    }
    // online softmax: each q-row lives across 16 lanes (lane&15) x 4 nb
    float alpha[4];
#pragma unroll
    for (int r = 0; r < 4; r++) {
      float mx = fmaxf(fmaxf(s[0][r], s[1][r]), fmaxf(s[2][r], s[3][r]));
      mx = fmaxf(mx, __shfl_xor(mx, 1, 64));
      mx = fmaxf(mx, __shfl_xor(mx, 2, 64));
      mx = fmaxf(mx, __shfl_xor(mx, 4, 64));
      mx = fmaxf(mx, __shfl_xor(mx, 8, 64));
      float mn = fmaxf(m_r[r], mx);
      alpha[r] = __expf(m_r[r] - mn);
      m_r[r] = mn;
      float rs = 0.f;
#pragma unroll
      for (int nb = 0; nb < 4; nb++) {
        float p = __expf(s[nb][r] - mn);
        s[nb][r] = p;
        rs += p;
      }
      rs += __shfl_xor(rs, 1, 64);
      rs += __shfl_xor(rs, 2, 64);
      rs += __shfl_xor(rs, 4, 64);
      rs += __shfl_xor(rs, 8, 64);
      l_r[r] = l_r[r] * alpha[r] + rs;
    }
    // P -> wave-private LDS (bf16, swizzled), rescale O, then PV
#pragma unroll
    for (int nb = 0; nb < 4; nb++)
#pragma unroll
      for (int r = 0; r < 4; r++) {
        int q = l4 * 4 + r;
        *(u16*)(Pb + ((q * 128 + (nb * 16 + l15) * 2) ^ ((q & 7) << 4))) =
            f2bf(s[nb][r]);
      }
#pragma unroll
    for (int nd = 0; nd < 4; nd++)
#pragma unroll
      for (int r = 0; r < 4; r++) o[nd][r] *= alpha[r];
    asm volatile("s_waitcnt lgkmcnt(0)" ::: "memory");  // wave-local P ready
    bf16x8 pa0 = *(const bf16x8*)(Pb + ((l15 * 128 + l4 * 16) ^ ((l15 & 7) << 4)));
    bf16x8 pa1 = *(const bf16x8*)(Pb + ((l15 * 128 + 64 + l4 * 16) ^ ((l15 & 7) << 4)));
#pragma unroll
    for (int nd = 0; nd < 4; nd++) {
      int row = nd * 16 + l15;
      bf16x8 vf0 = *(const bf16x8*)(Vb + ((row * 128 + l4 * 16) ^ ((row & 7) << 4)));
      bf16x8 vf1 = *(const bf16x8*)(Vb + ((row * 128 + 64 + l4 * 16) ^ ((row & 7) << 4)));
      __builtin_amdgcn_s_setprio(1);
      o[nd] = MFMA(pa0, vf0, o[nd]);
      o[nd] = MFMA(pa1, vf1, o[nd]);
      __builtin_amdgcn_s_setprio(0);
    }
    __syncthreads();  // all reads of Kl/Vt done before next overwrite
  }
  // writeback ctx (bf16, [B,S,D] layout)
  size_t orow = rowbase + (size_t)qt * 64 + w * 16 + l4 * 4;
#pragma unroll
  for (int nd = 0; nd < 4; nd++)
#pragma unroll
    for (int r = 0; r < 4; r++) {
      float vv = o[nd][r] / l_r[r];
      ctx[(orow + r) * DD + hcol + nd * 16 + l15] = f2bf(vv);
    }
}

extern "C" void kernel_launch(void* const* d_in, const int* in_sizes, int n_in,
                              void* d_out, int out_size, void* d_ws, size_t ws_size,
                              hipStream_t stream) {
  const float* x  = (const float*)d_in[0];
  // d_in[1] = mask (causal, hard-coded in k_attn)
  const float* Wq = (const float*)d_in[2];
  const float* bq = (const float*)d_in[3];
  const float* Wk = (const float*)d_in[4];
  const float* bk = (const float*)d_in[5];
  const float* Wv = (const float*)d_in[6];
  const float* bv = (const float*)d_in[7];
  const float* Wo = (const float*)d_in[8];
  const float* bo = (const float*)d_in[9];
  float* out = (float*)d_out;

  char* ws = (char*)d_ws;
  const size_t XN = (size_t)MROWS * DD;  // 3,145,728
  const size_t WN = (size_t)DD * DD;     // 589,824
  u16* xb  = (u16*)ws;                                 // XN
  u16* Wt  = (u16*)(ws + XN * 2);                      // 4*WN
  u16* qkv = (u16*)(ws + XN * 2 + WN * 8);             // 3*XN
  u16* ctx = (u16*)(ws + XN * 2 + WN * 8 + XN * 6);    // XN

  k_convert<<<dim3((int)(XN / 1024)), 256, 0, stream>>>(x, xb, (int)XN);
  k_transpose_w<<<dim3(24, 24, 4), 256, 0, stream>>>(Wq, Wk, Wv, Wo, Wt);
  k_gemm_qkv<<<dim3(32, 6, 3), 256, 0, stream>>>(xb, Wt, bq, bk, bv, qkv);
  k_attn<<<dim3(24, 32), 256, 0, stream>>>(qkv, qkv + XN, qkv + 2 * XN, ctx);
  k_gemm_out<<<dim3(32, 6), 256, 0, stream>>>(ctx, Wt + 3 * WN, bo, out);
}

// Round 3
// 153.618 us; speedup vs baseline: 1.1512x; 1.0089x over previous
//
#include <hip/hip_runtime.h>

typedef unsigned short u16;
typedef unsigned int u32;
typedef short bf16x8 __attribute__((ext_vector_type(8)));
typedef float f32x4 __attribute__((ext_vector_type(4)));

#define MFMA(a, b, c) __builtin_amdgcn_mfma_f32_16x16x32_bf16((a), (b), (c), 0, 0, 0)

#define BB 2
#define SS 2048
#define DD 768
#define HH 12
#define MROWS (BB * SS) /* 4096 */

__device__ __forceinline__ u16 f2bf(float f) {
  u32 u = __float_as_uint(f);
  u += 0x7FFFu + ((u >> 16) & 1u);  // round-to-nearest-even
  return (u16)(u >> 16);
}

// ---------------- convert x (fp32 -> bf16) ----------------
__global__ __launch_bounds__(256) void k_convert(const float* __restrict__ in,
                                                 u16* __restrict__ out, int n) {
  int i = (blockIdx.x * 256 + threadIdx.x) * 4;
  if (i < n) {
    float4 v = *(const float4*)(in + i);
    ushort4 o;
    o.x = f2bf(v.x); o.y = f2bf(v.y); o.z = f2bf(v.z); o.w = f2bf(v.w);
    *(ushort4*)(out + i) = o;
  }
}

// ------- transpose+convert the 4 weight matrices: out[z][n][k] = W_z[k][n] -------
__global__ __launch_bounds__(256) void k_transpose_w(
    const float* __restrict__ Wq, const float* __restrict__ Wk,
    const float* __restrict__ Wv, const float* __restrict__ Wo,
    u16* __restrict__ out) {
  const float* W = (blockIdx.z == 0) ? Wq : (blockIdx.z == 1) ? Wk
                   : (blockIdx.z == 2) ? Wv : Wo;
  u16* o = out + (size_t)blockIdx.z * DD * DD;
  __shared__ float tile[32][33];
  int kt = blockIdx.x * 32, nt = blockIdx.y * 32;
  int tx = threadIdx.x & 31, ty = threadIdx.x >> 5;
#pragma unroll
  for (int r = 0; r < 4; r++) {
    int row = ty + r * 8;
    tile[row][tx] = W[(size_t)(kt + row) * DD + nt + tx];
  }
  __syncthreads();
#pragma unroll
  for (int r = 0; r < 4; r++) {
    int row = ty + r * 8;
    o[(size_t)(nt + row) * DD + kt + tx] = f2bf(tile[tx][row]);
  }
}

// ---------------- 128x128-tile bf16 MFMA GEMM: C = A @ Bt^T + bias ----------------
// A: [M x 768] bf16 row-major. Bt: [768 x 768] bf16 with Bt[n][k] = B[k][n].
template <bool OUT_BF16>
__device__ __forceinline__ void gemm128(const u16* __restrict__ A,
                                        const u16* __restrict__ Bt,
                                        const float* __restrict__ bias,
                                        void* __restrict__ Cout, int m0, int n0) {
  __shared__ __align__(16) u16 Al[128 * 40];  // [m][k], pad 40
  __shared__ __align__(16) u16 Bl[128 * 40];  // [n][k]
  int t = threadIdx.x;
  int lane = t & 63, w = t >> 6;
  int wm = (w >> 1) * 64, wn = (w & 1) * 64;
  int l15 = lane & 15, l4 = lane >> 4;
  f32x4 acc[4][4];
#pragma unroll
  for (int i = 0; i < 4; i++)
#pragma unroll
    for (int j = 0; j < 4; j++) acc[i][j] = (f32x4){0.f, 0.f, 0.f, 0.f};

  for (int k0 = 0; k0 < DD; k0 += 32) {
#pragma unroll
    for (int rep = 0; rep < 2; rep++) {
      int idx = rep * 256 + t;
      int row = idx >> 2, k8 = (idx & 3) << 3;
      *(uint4*)(&Al[row * 40 + k8]) =
          *(const uint4*)(A + (size_t)(m0 + row) * DD + k0 + k8);
      *(uint4*)(&Bl[row * 40 + k8]) =
          *(const uint4*)(Bt + (size_t)(n0 + row) * DD + k0 + k8);
    }
    __syncthreads();
    bf16x8 af[4], bfr[4];
#pragma unroll
    for (int mb = 0; mb < 4; mb++)
      af[mb] = *(const bf16x8*)(&Al[(wm + mb * 16 + l15) * 40 + l4 * 8]);
#pragma unroll
    for (int nb = 0; nb < 4; nb++)
      bfr[nb] = *(const bf16x8*)(&Bl[(wn + nb * 16 + l15) * 40 + l4 * 8]);
    __builtin_amdgcn_s_setprio(1);
#pragma unroll
    for (int mb = 0; mb < 4; mb++)
#pragma unroll
      for (int nb = 0; nb < 4; nb++)
        acc[mb][nb] = MFMA(af[mb], bfr[nb], acc[mb][nb]);
    __builtin_amdgcn_s_setprio(0);
    __syncthreads();
  }
  // epilogue: C/D layout col=lane&15, row=(lane>>4)*4+reg  [verified m89/m91]
#pragma unroll
  for (int nb = 0; nb < 4; nb++) {
    int col = n0 + wn + nb * 16 + l15;
    float bs = bias[col];
#pragma unroll
    for (int mb = 0; mb < 4; mb++) {
#pragma unroll
      for (int r = 0; r < 4; r++) {
        int row = m0 + wm + mb * 16 + l4 * 4 + r;
        float vv = acc[mb][nb][r] + bs;
        if (OUT_BF16)
          ((u16*)Cout)[(size_t)row * DD + col] = f2bf(vv);
        else
          ((float*)Cout)[(size_t)row * DD + col] = vv;
      }
    }
  }
}

__global__ __launch_bounds__(256) void k_gemm_qkv(
    const u16* __restrict__ xb, const u16* __restrict__ Wt,
    const float* __restrict__ bq, const float* __restrict__ bk,
    const float* __restrict__ bv, u16* __restrict__ qkv) {
  int z = blockIdx.z;
  const u16* Bt = Wt + (size_t)z * DD * DD;
  const float* bias = (z == 0) ? bq : (z == 1) ? bk : bv;
  u16* out = qkv + (size_t)z * MROWS * DD;
  gemm128<true>(xb, Bt, bias, out, blockIdx.x * 128, blockIdx.y * 128);
}

__global__ __launch_bounds__(256) void k_gemm_out(
    const u16* __restrict__ ctx, const u16* __restrict__ Wot,
    const float* __restrict__ bo, float* __restrict__ out) {
  gemm128<false>(ctx, Wot, bo, out, blockIdx.x * 128, blockIdx.y * 128);
}

// ---------------- flash attention (causal) ----------------
// grid: (B*H, S/64). 256 threads = 4 waves; wave w owns 16 Q-rows.
// qt = 31 - blockIdx.y: LPT (longest blocks dispatch first).
// LDS: XOR-swizzled, stored_addr(row,col) = (row*128 + col_b) ^ ((row&7)<<4).
// Staging geometry row=lane: V-transpose u16 writes are 64-lane-contiguous
// (conflict-free); K b128 writes hit the 8-dword/bank wave64 floor.
__global__ __launch_bounds__(256) void k_attn(const u16* __restrict__ qb,
                                              const u16* __restrict__ kb,
                                              const u16* __restrict__ vb,
                                              u16* __restrict__ ctx) {
  __shared__ __align__(16) u16 Kl[64 * 64];      // K tile [j][d], swizzled
  __shared__ __align__(16) u16 Vt[64 * 64];      // V tile transposed [d][j], swizzled
  __shared__ __align__(16) u16 Pl[4 * 16 * 64];  // per-wave P [q][j], swizzled
  int qt = (int)gridDim.y - 1 - (int)blockIdx.y;  // descending qt = LPT order
  int bh = blockIdx.x;
  int b = bh / HH, h = bh % HH;
  int t = threadIdx.x, w = t >> 6, lane = t & 63;
  int l15 = lane & 15, l4 = lane >> 4;
  size_t rowbase = (size_t)b * SS;
  int hcol = h * 64;

  // Q fragments stay in registers for the whole block
  int qrow = qt * 64 + w * 16 + l15;
  const u16* qptr = qb + (rowbase + qrow) * DD + hcol;
  bf16x8 qf0 = *(const bf16x8*)(qptr + l4 * 8);
  bf16x8 qf1 = *(const bf16x8*)(qptr + 32 + l4 * 8);

  float m_r[4], l_r[4];
  f32x4 o[4];
#pragma unroll
  for (int r = 0; r < 4; r++) { m_r[r] = -3e38f; l_r[r] = 0.f; }
#pragma unroll
  for (int nd = 0; nd < 4; nd++) o[nd] = (f32x4){0.f, 0.f, 0.f, 0.f};

  char* Kb = (char*)Kl;
  char* Vb = (char*)Vt;
  char* Pb = (char*)(Pl + w * 16 * 64);
  const u16* kbase = kb + rowbase * DD + hcol;
  const u16* vbase = vb + rowbase * DD + hcol;
  // staging geometry: row = lane, wave w covers u16 columns {w*8.., w*8+32..}
  int jj = lane, dblk = w * 8;
  const f32x4 z4 = {0.f, 0.f, 0.f, 0.f};

  uint4 kr[2], vr[2];
  // prologue: load tile 0
#pragma unroll
  for (int rep = 0; rep < 2; rep++) {
    int d8 = dblk + rep * 32;
    kr[rep] = *(const uint4*)(kbase + (size_t)jj * DD + d8);
    vr[rep] = *(const uint4*)(vbase + (size_t)jj * DD + d8);
  }

  for (int kt = 0; kt <= qt; kt++) {
    // write staged registers -> LDS (swizzled)
#pragma unroll
    for (int rep = 0; rep < 2; rep++) {
      int d8 = dblk + rep * 32;
      *(uint4*)(Kb + ((jj * 128 + d8 * 2) ^ ((jj & 7) << 4))) = kr[rep];
      u16 el[8];
      *(uint4*)el = vr[rep];
#pragma unroll
      for (int i = 0; i < 8; i++) {
        int d = d8 + i;
        *(u16*)(Vb + ((d * 128 + jj * 2) ^ ((d & 7) << 4))) = el[i];
      }
    }
    __syncthreads();
    // issue next tile's global loads early (latency hidden under compute)
    if (kt < qt) {
#pragma unroll
      for (int rep = 0; rep < 2; rep++) {
        int row = (kt + 1) * 64 + jj;
        int d8 = dblk + rep * 32;
        kr[rep] = *(const uint4*)(kbase + (size_t)row * DD + d8);
        vr[rep] = *(const uint4*)(vbase + (size_t)row * DD + d8);
      }
    }

    // S = Q K^T
    f32x4 sacc[4];
#pragma unroll
    for (int nb = 0; nb < 4; nb++) {
      int row = nb * 16 + l15;
      bf16x8 kf0 = *(const bf16x8*)(Kb + ((row * 128 + l4 * 16) ^ ((row & 7) << 4)));
      bf16x8 kf1 = *(const bf16x8*)(Kb + ((row * 128 + 64 + l4 * 16) ^ ((row & 7) << 4)));
      __builtin_amdgcn_s_setprio(1);
      sacc[nb] = MFMA(qf0, kf0, z4);
      sacc[nb] = MFMA(qf1, kf1, sacc[nb]);
      __builtin_amdgcn_s_setprio(0);
    }
    float s[4][4];
#pragma unroll
    for (int nb = 0; nb < 4; nb++)
#pragma unroll
      for (int r = 0; r < 4; r++) s[nb][r] = sacc[nb][r] * 0.125f;
    if (kt == qt) {  // diagonal tile: causal mask (tile-local indices valid)
#pragma unroll
      for (int nb = 0; nb < 4; nb++) {
        int jg = nb * 16 + l15;
#pragma unroll
        for (int r = 0; r < 4; r++) {
          int qg = w * 16 + l4 * 4 + r;
          if (jg > qg) s[nb][r] = -1e30f;
        }
      }
    }
    // online softmax: each q-row lives across 16 lanes (lane&15) x 4 nb
    float alpha[4];
#pragma unroll
    for (int r = 0; r < 4; r++) {
      float mx = fmaxf(fmaxf(s[0][r], s[1][r]), fmaxf(s[2][r], s[3][r]));
      mx = fmaxf(mx, __shfl_xor(mx, 1, 64));
      mx = fmaxf(mx, __shfl_xor(mx, 2, 64));
      mx = fmaxf(mx, __shfl_xor(mx, 4, 64));
      mx = fmaxf(mx, __shfl_xor(mx, 8, 64));
      float mn = fmaxf(m_r[r], mx);
      alpha[r] = __expf(m_r[r] - mn);
      m_r[r] = mn;
      float rs = 0.f;
#pragma unroll
      for (int nb = 0; nb < 4; nb++) {
        float p = __expf(s[nb][r] - mn);
        s[nb][r] = p;
        rs += p;
      }
      rs += __shfl_xor(rs, 1, 64);
      rs += __shfl_xor(rs, 2, 64);
      rs += __shfl_xor(rs, 4, 64);
      rs += __shfl_xor(rs, 8, 64);
      l_r[r] = l_r[r] * alpha[r] + rs;
    }
    // P -> wave-private LDS (bf16, swizzled), rescale O, then PV
#pragma unroll
    for (int nb = 0; nb < 4; nb++)
#pragma unroll
      for (int r = 0; r < 4; r++) {
        int q = l4 * 4 + r;
        *(u16*)(Pb + ((q * 128 + (nb * 16 + l15) * 2) ^ ((q & 7) << 4))) =
            f2bf(s[nb][r]);
      }
#pragma unroll
    for (int nd = 0; nd < 4; nd++)
#pragma unroll
      for (int r = 0; r < 4; r++) o[nd][r] *= alpha[r];
    asm volatile("s_waitcnt lgkmcnt(0)" ::: "memory");  // wave-local P ready
    bf16x8 pa0 = *(const bf16x8*)(Pb + ((l15 * 128 + l4 * 16) ^ ((l15 & 7) << 4)));
    bf16x8 pa1 = *(const bf16x8*)(Pb + ((l15 * 128 + 64 + l4 * 16) ^ ((l15 & 7) << 4)));
#pragma unroll
    for (int nd = 0; nd < 4; nd++) {
      int row = nd * 16 + l15;
      bf16x8 vf0 = *(const bf16x8*)(Vb + ((row * 128 + l4 * 16) ^ ((row & 7) << 4)));
      bf16x8 vf1 = *(const bf16x8*)(Vb + ((row * 128 + 64 + l4 * 16) ^ ((row & 7) << 4)));
      __builtin_amdgcn_s_setprio(1);
      o[nd] = MFMA(pa0, vf0, o[nd]);
      o[nd] = MFMA(pa1, vf1, o[nd]);
      __builtin_amdgcn_s_setprio(0);
    }
    __syncthreads();  // all reads of Kl/Vt done before next overwrite
  }
  // writeback ctx (bf16, [B,S,D] layout)
  size_t orow = rowbase + (size_t)qt * 64 + w * 16 + l4 * 4;
#pragma unroll
  for (int nd = 0; nd < 4; nd++)
#pragma unroll
    for (int r = 0; r < 4; r++) {
      float vv = o[nd][r] / l_r[r];
      ctx[(orow + r) * DD + hcol + nd * 16 + l15] = f2bf(vv);
    }
}

extern "C" void kernel_launch(void* const* d_in, const int* in_sizes, int n_in,
                              void* d_out, int out_size, void* d_ws, size_t ws_size,
                              hipStream_t stream) {
  const float* x  = (const float*)d_in[0];
  // d_in[1] = mask (causal, hard-coded in k_attn)
  const float* Wq = (const float*)d_in[2];
  const float* bq = (const float*)d_in[3];
  const float* Wk = (const float*)d_in[4];
  const float* bk = (const float*)d_in[5];
  const float* Wv = (const float*)d_in[6];
  const float* bv = (const float*)d_in[7];
  const float* Wo = (const float*)d_in[8];
  const float* bo = (const float*)d_in[9];
  float* out = (float*)d_out;

  char* ws = (char*)d_ws;
  const size_t XN = (size_t)MROWS * DD;  // 3,145,728
  const size_t WN = (size_t)DD * DD;     // 589,824
  u16* xb  = (u16*)ws;                                 // XN
  u16* Wt  = (u16*)(ws + XN * 2);                      // 4*WN
  u16* qkv = (u16*)(ws + XN * 2 + WN * 8);             // 3*XN
  u16* ctx = (u16*)(ws + XN * 2 + WN * 8 + XN * 6);    // XN

  k_convert<<<dim3((int)(XN / 1024)), 256, 0, stream>>>(x, xb, (int)XN);
  k_transpose_w<<<dim3(24, 24, 4), 256, 0, stream>>>(Wq, Wk, Wv, Wo, Wt);
  k_gemm_qkv<<<dim3(32, 6, 3), 256, 0, stream>>>(xb, Wt, bq, bk, bv, qkv);
  k_attn<<<dim3(24, 32), 256, 0, stream>>>(qkv, qkv + XN, qkv + 2 * XN, ctx);
  k_gemm_out<<<dim3(32, 6), 256, 0, stream>>>(ctx, Wt + 3 * WN, bo, out);
}

// Round 4
// 129.807 us; speedup vs baseline: 1.3624x; 1.1834x over previous
//
#include <hip/hip_runtime.h>

typedef unsigned short u16;
typedef unsigned int u32;
typedef unsigned long long u64;
typedef short bf16x8 __attribute__((ext_vector_type(8)));
typedef float f32x4 __attribute__((ext_vector_type(4)));

#define MFMA(a, b, c) __builtin_amdgcn_mfma_f32_16x16x32_bf16((a), (b), (c), 0, 0, 0)

#define BB 2
#define SS 2048
#define DD 768
#define HH 12
#define MROWS (BB * SS) /* 4096 */
#define NSLOT 80         /* K-split chunks per (b,h): 32+24+16+8 */

#if defined(__has_builtin)
#if __has_builtin(__builtin_amdgcn_global_load_lds)
#define HAS_GLL 1
#endif
#endif
#ifndef HAS_GLL
#define HAS_GLL 0
#endif

__device__ __forceinline__ u16 f2bf(float f) {
  u32 u = __float_as_uint(f);
  u += 0x7FFFu + ((u >> 16) & 1u);  // round-to-nearest-even
  return (u16)(u >> 16);
}
__device__ __forceinline__ float bf2f(u16 v) {
  return __uint_as_float(((u32)v) << 16);
}

#if HAS_GLL
// lane i's 16B from per-lane global addr -> ldsbase + i*16 (linear). [m97]
__device__ __forceinline__ void gload_lds16(const u16* g, u16* l) {
  __builtin_amdgcn_global_load_lds(
      (const __attribute__((address_space(1))) void*)(u64)(uintptr_t)g,
      (__attribute__((address_space(3))) void*)(u64)(uintptr_t)l, 16, 0, 0);
}
#endif

// ---------------- convert x (fp32 -> bf16) ----------------
__global__ __launch_bounds__(256) void k_convert(const float* __restrict__ in,
                                                 u16* __restrict__ out, int n) {
  int i = (blockIdx.x * 256 + threadIdx.x) * 4;
  if (i < n) {
    float4 v = *(const float4*)(in + i);
    ushort4 o;
    o.x = f2bf(v.x); o.y = f2bf(v.y); o.z = f2bf(v.z); o.w = f2bf(v.w);
    *(ushort4*)(out + i) = o;
  }
}

// ------- transpose+convert the 4 weight matrices: out[z][n][k] = W_z[k][n] -------
__global__ __launch_bounds__(256) void k_transpose_w(
    const float* __restrict__ Wq, const float* __restrict__ Wk,
    const float* __restrict__ Wv, const float* __restrict__ Wo,
    u16* __restrict__ out) {
  const float* W = (blockIdx.z == 0) ? Wq : (blockIdx.z == 1) ? Wk
                   : (blockIdx.z == 2) ? Wv : Wo;
  u16* o = out + (size_t)blockIdx.z * DD * DD;
  __shared__ float tile[32][33];
  int kt = blockIdx.x * 32, nt = blockIdx.y * 32;
  int tx = threadIdx.x & 31, ty = threadIdx.x >> 5;
#pragma unroll
  for (int r = 0; r < 4; r++) {
    int row = ty + r * 8;
    tile[row][tx] = W[(size_t)(kt + row) * DD + nt + tx];
  }
  __syncthreads();
#pragma unroll
  for (int r = 0; r < 4; r++) {
    int row = ty + r * 8;
    o[(size_t)(nt + row) * DD + kt + tx] = f2bf(tile[tx][row]);
  }
}

// ------- 128x128-tile bf16 MFMA GEMM (m97 structure): C = A @ Bt^T + bias -------
// Linear LDS [row][32] u16 (64B rows): ds_read_b128 hits the 8-dword/bank floor.
template <bool OUT_BF16>
__device__ __forceinline__ void gemm128(const u16* __restrict__ A,
                                        const u16* __restrict__ Bt,
                                        const float* __restrict__ bias,
                                        void* __restrict__ Cout, int m0, int n0) {
  __shared__ __align__(16) u16 Al[128 * 32];
  __shared__ __align__(16) u16 Bl[128 * 32];
  int t = threadIdx.x;
  int lane = t & 63, w = t >> 6;
  int wm = (w >> 1) * 64, wn = (w & 1) * 64;
  int l15 = lane & 15, l4 = lane >> 4;
  f32x4 acc[4][4];
#pragma unroll
  for (int i = 0; i < 4; i++)
#pragma unroll
    for (int j = 0; j < 4; j++) acc[i][j] = (f32x4){0.f, 0.f, 0.f, 0.f};

#if HAS_GLL
  int srow = w * 32 + (lane >> 2);  // wave w stages rows w*32..w*32+31
  int skc = (lane & 3) * 8;
#endif

  for (int k0 = 0; k0 < DD; k0 += 32) {
#if HAS_GLL
#pragma unroll
    for (int rep = 0; rep < 2; rep++) {
      int row = srow + rep * 16;
      gload_lds16(A + (size_t)(m0 + row) * DD + k0 + skc,
                  &Al[(w * 32 + rep * 16) * 32]);
      gload_lds16(Bt + (size_t)(n0 + row) * DD + k0 + skc,
                  &Bl[(w * 32 + rep * 16) * 32]);
    }
#else
#pragma unroll
    for (int rep = 0; rep < 2; rep++) {
      int idx = rep * 256 + t;
      int row = idx >> 2, kc = (idx & 3) * 8;
      *(uint4*)&Al[row * 32 + kc] =
          *(const uint4*)(A + (size_t)(m0 + row) * DD + k0 + kc);
      *(uint4*)&Bl[row * 32 + kc] =
          *(const uint4*)(Bt + (size_t)(n0 + row) * DD + k0 + kc);
    }
#endif
    __syncthreads();
    bf16x8 af[4], bfr[4];
#pragma unroll
    for (int mb = 0; mb < 4; mb++)
      af[mb] = *(const bf16x8*)(&Al[(wm + mb * 16 + l15) * 32 + l4 * 8]);
#pragma unroll
    for (int nb = 0; nb < 4; nb++)
      bfr[nb] = *(const bf16x8*)(&Bl[(wn + nb * 16 + l15) * 32 + l4 * 8]);
#pragma unroll
    for (int mb = 0; mb < 4; mb++)
#pragma unroll
      for (int nb = 0; nb < 4; nb++)
        acc[mb][nb] = MFMA(af[mb], bfr[nb], acc[mb][nb]);
    __syncthreads();
  }
  // epilogue: C/D layout col=lane&15, row=(lane>>4)*4+reg  [verified m89/m91]
#pragma unroll
  for (int nb = 0; nb < 4; nb++) {
    int col = n0 + wn + nb * 16 + l15;
    float bs = bias[col];
#pragma unroll
    for (int mb = 0; mb < 4; mb++) {
#pragma unroll
      for (int r = 0; r < 4; r++) {
        int row = m0 + wm + mb * 16 + l4 * 4 + r;
        float vv = acc[mb][nb][r] + bs;
        if (OUT_BF16)
          ((u16*)Cout)[(size_t)row * DD + col] = f2bf(vv);
        else
          ((float*)Cout)[(size_t)row * DD + col] = vv;
      }
    }
  }
}

__global__ __launch_bounds__(256) void k_gemm_qkv(
    const u16* __restrict__ xb, const u16* __restrict__ Wt,
    const float* __restrict__ bq, const float* __restrict__ bk,
    const float* __restrict__ bv, u16* __restrict__ qkv) {
  int z = blockIdx.z;
  const u16* Bt = Wt + (size_t)z * DD * DD;
  const float* bias = (z == 0) ? bq : (z == 1) ? bk : bv;
  u16* out = qkv + (size_t)z * MROWS * DD;
  gemm128<true>(xb, Bt, bias, out, blockIdx.x * 128, blockIdx.y * 128);
}

__global__ __launch_bounds__(256) void k_gemm_out(
    const u16* __restrict__ ctx, const u16* __restrict__ Wot,
    const float* __restrict__ bo, float* __restrict__ out) {
  gemm128<false>(ctx, Wot, bo, out, blockIdx.x * 128, blockIdx.y * 128);
}

// ================= flash attention, K-split =================
// grid (24 bh, 80 slots). slot -> (qt, c): chunk c of n=ceil((qt+1)/8) handles
// kt in {c, c+n, ...} (len = (qt-c)/n+1 tiles, <=8). Partials: normalized O
// (bf16) + m,l (f32). LDS XOR-swizzled, addr = (row*128 + col_b) ^ ((row&7)<<4).
__global__ __launch_bounds__(256) void k_attn_split(
    const u16* __restrict__ qb, const u16* __restrict__ kb,
    const u16* __restrict__ vb, u16* __restrict__ PO,
    float* __restrict__ PM, float* __restrict__ PL) {
  __shared__ __align__(16) u16 Kl[64 * 64];
  __shared__ __align__(16) u16 Vt[64 * 64];
  __shared__ __align__(16) u16 Pl[4 * 16 * 64];
  int bh = blockIdx.x;
  int slot = blockIdx.y;
  int c, qt;
  if (slot < 32)      { c = 0; qt = 31 - slot; }
  else if (slot < 56) { c = 1; qt = 31 - (slot - 32); }
  else if (slot < 72) { c = 2; qt = 31 - (slot - 56); }
  else                { c = 3; qt = 31 - (slot - 72); }
  int n = (qt >> 3) + 1;
  int len = (qt - c) / n + 1;

  int b = bh / HH, h = bh % HH;
  int t = threadIdx.x, w = t >> 6, lane = t & 63;
  int l15 = lane & 15, l4 = lane >> 4;
  size_t rowbase = (size_t)b * SS;
  int hcol = h * 64;

  int qrow = qt * 64 + w * 16 + l15;
  const u16* qptr = qb + (rowbase + qrow) * DD + hcol;
  bf16x8 qf0 = *(const bf16x8*)(qptr + l4 * 8);
  bf16x8 qf1 = *(const bf16x8*)(qptr + 32 + l4 * 8);

  float m_r[4], l_r[4];
  f32x4 o[4];
#pragma unroll
  for (int r = 0; r < 4; r++) { m_r[r] = -3e38f; l_r[r] = 0.f; }
#pragma unroll
  for (int nd = 0; nd < 4; nd++) o[nd] = (f32x4){0.f, 0.f, 0.f, 0.f};

  char* Kb = (char*)Kl;
  char* Vb = (char*)Vt;
  char* Pb = (char*)(Pl + w * 16 * 64);
  const u16* kbase = kb + rowbase * DD + hcol;
  const u16* vbase = vb + rowbase * DD + hcol;
  int jj = lane, dblk = w * 8;
  const f32x4 z4 = {0.f, 0.f, 0.f, 0.f};

  uint4 kr[2], vr[2];
#pragma unroll
  for (int rep = 0; rep < 2; rep++) {
    int d8 = dblk + rep * 32;
    kr[rep] = *(const uint4*)(kbase + (size_t)(c * 64 + jj) * DD + d8);
    vr[rep] = *(const uint4*)(vbase + (size_t)(c * 64 + jj) * DD + d8);
  }

  for (int i = 0; i < len; i++) {
    int kt = c + i * n;
#pragma unroll
    for (int rep = 0; rep < 2; rep++) {
      int d8 = dblk + rep * 32;
      *(uint4*)(Kb + ((jj * 128 + d8 * 2) ^ ((jj & 7) << 4))) = kr[rep];
      u16 el[8];
      *(uint4*)el = vr[rep];
#pragma unroll
      for (int ii = 0; ii < 8; ii++) {
        int d = d8 + ii;
        *(u16*)(Vb + ((d * 128 + jj * 2) ^ ((d & 7) << 4))) = el[ii];
      }
    }
    __syncthreads();
    if (i + 1 < len) {
#pragma unroll
      for (int rep = 0; rep < 2; rep++) {
        int row = (kt + n) * 64 + jj;
        int d8 = dblk + rep * 32;
        kr[rep] = *(const uint4*)(kbase + (size_t)row * DD + d8);
        vr[rep] = *(const uint4*)(vbase + (size_t)row * DD + d8);
      }
    }

    // S = Q K^T
    f32x4 sacc[4];
#pragma unroll
    for (int nb = 0; nb < 4; nb++) {
      int row = nb * 16 + l15;
      bf16x8 kf0 = *(const bf16x8*)(Kb + ((row * 128 + l4 * 16) ^ ((row & 7) << 4)));
      bf16x8 kf1 = *(const bf16x8*)(Kb + ((row * 128 + 64 + l4 * 16) ^ ((row & 7) << 4)));
      __builtin_amdgcn_s_setprio(1);
      sacc[nb] = MFMA(qf0, kf0, z4);
      sacc[nb] = MFMA(qf1, kf1, sacc[nb]);
      __builtin_amdgcn_s_setprio(0);
    }
    float s[4][4];
#pragma unroll
    for (int nb = 0; nb < 4; nb++)
#pragma unroll
      for (int r = 0; r < 4; r++) s[nb][r] = sacc[nb][r] * 0.125f;
    if (kt == qt) {  // diagonal tile: causal mask
#pragma unroll
      for (int nb = 0; nb < 4; nb++) {
        int jg = nb * 16 + l15;
#pragma unroll
        for (int r = 0; r < 4; r++) {
          int qg = w * 16 + l4 * 4 + r;
          if (jg > qg) s[nb][r] = -1e30f;
        }
      }
    }
    // online softmax (q-row spread over 16 lanes x 4 nb)
    float alpha[4];
#pragma unroll
    for (int r = 0; r < 4; r++) {
      float mx = fmaxf(fmaxf(s[0][r], s[1][r]), fmaxf(s[2][r], s[3][r]));
      mx = fmaxf(mx, __shfl_xor(mx, 1, 64));
      mx = fmaxf(mx, __shfl_xor(mx, 2, 64));
      mx = fmaxf(mx, __shfl_xor(mx, 4, 64));
      mx = fmaxf(mx, __shfl_xor(mx, 8, 64));
      float mn = fmaxf(m_r[r], mx);
      alpha[r] = __expf(m_r[r] - mn);
      m_r[r] = mn;
      float rs = 0.f;
#pragma unroll
      for (int nb = 0; nb < 4; nb++) {
        float p = __expf(s[nb][r] - mn);
        s[nb][r] = p;
        rs += p;
      }
      rs += __shfl_xor(rs, 1, 64);
      rs += __shfl_xor(rs, 2, 64);
      rs += __shfl_xor(rs, 4, 64);
      rs += __shfl_xor(rs, 8, 64);
      l_r[r] = l_r[r] * alpha[r] + rs;
    }
    // P -> wave-private LDS, rescale O, PV
#pragma unroll
    for (int nb = 0; nb < 4; nb++)
#pragma unroll
      for (int r = 0; r < 4; r++) {
        int q = l4 * 4 + r;
        *(u16*)(Pb + ((q * 128 + (nb * 16 + l15) * 2) ^ ((q & 7) << 4))) =
            f2bf(s[nb][r]);
      }
#pragma unroll
    for (int nd = 0; nd < 4; nd++)
#pragma unroll
      for (int r = 0; r < 4; r++) o[nd][r] *= alpha[r];
    asm volatile("s_waitcnt lgkmcnt(0)" ::: "memory");
    bf16x8 pa0 = *(const bf16x8*)(Pb + ((l15 * 128 + l4 * 16) ^ ((l15 & 7) << 4)));
    bf16x8 pa1 = *(const bf16x8*)(Pb + ((l15 * 128 + 64 + l4 * 16) ^ ((l15 & 7) << 4)));
#pragma unroll
    for (int nd = 0; nd < 4; nd++) {
      int row = nd * 16 + l15;
      bf16x8 vf0 = *(const bf16x8*)(Vb + ((row * 128 + l4 * 16) ^ ((row & 7) << 4)));
      bf16x8 vf1 = *(const bf16x8*)(Vb + ((row * 128 + 64 + l4 * 16) ^ ((row & 7) << 4)));
      __builtin_amdgcn_s_setprio(1);
      o[nd] = MFMA(pa0, vf0, o[nd]);
      o[nd] = MFMA(pa1, vf1, o[nd]);
      __builtin_amdgcn_s_setprio(0);
    }
    __syncthreads();
  }
  // write partial: normalized O (bf16) + m,l (f32)
  int gs = bh * NSLOT + slot;
  u16* po = PO + (size_t)gs * 4096;
#pragma unroll
  for (int nd = 0; nd < 4; nd++)
#pragma unroll
    for (int r = 0; r < 4; r++)
      po[(w * 16 + l4 * 4 + r) * 64 + nd * 16 + l15] = f2bf(o[nd][r] / l_r[r]);
  if (l15 == 0) {
#pragma unroll
    for (int r = 0; r < 4; r++) {
      int q = w * 16 + l4 * 4 + r;
      PM[gs * 64 + q] = m_r[r];
      PL[gs * 64 + q] = l_r[r];
    }
  }
}

// combine partials -> ctx. grid (24 bh, 32 qt), 256 threads: t -> row t>>2,
// 16-col segment (t&3)*16.
__global__ __launch_bounds__(256) void k_combine(const u16* __restrict__ PO,
                                                 const float* __restrict__ PM,
                                                 const float* __restrict__ PL,
                                                 u16* __restrict__ ctx) {
  int bh = blockIdx.x, qt = blockIdx.y;
  int b = bh / HH, h = bh % HH;
  int n = (qt >> 3) + 1;
  int t = threadIdx.x;
  int r = t >> 2, cs = (t & 3) << 4;
  const int sbase[4] = {0, 32, 56, 72};
  float wgt[4];
  size_t gidx[4];
  float M = -3e38f;
#pragma unroll
  for (int i = 0; i < 4; i++) {
    if (i < n) {
      int gs = bh * NSLOT + sbase[i] + (31 - qt);
      gidx[i] = (size_t)gs;
      float mi = PM[gs * 64 + r];
      wgt[i] = mi;  // stash m
      M = fmaxf(M, mi);
    }
  }
  float L = 0.f;
#pragma unroll
  for (int i = 0; i < 4; i++) {
    if (i < n) {
      float wi = PL[gidx[i] * 64 + r] * __expf(wgt[i] - M);
      wgt[i] = wi;
      L += wi;
    }
  }
  float inv = 1.f / L;
  float acc[16];
#pragma unroll
  for (int j = 0; j < 16; j++) acc[j] = 0.f;
#pragma unroll
  for (int i = 0; i < 4; i++) {
    if (i < n) {
      float wi = wgt[i] * inv;
      const u16* p = PO + gidx[i] * 4096 + r * 64 + cs;
      bf16x8 v0 = *(const bf16x8*)p;
      bf16x8 v1 = *(const bf16x8*)(p + 8);
#pragma unroll
      for (int j = 0; j < 8; j++) {
        acc[j]     += wi * bf2f((u16)v0[j]);
        acc[8 + j] += wi * bf2f((u16)v1[j]);
      }
    }
  }
  u16 ob[16];
#pragma unroll
  for (int j = 0; j < 16; j++) ob[j] = f2bf(acc[j]);
  u16* dst = ctx + ((size_t)b * SS + qt * 64 + r) * DD + h * 64 + cs;
  *(uint4*)dst = *(uint4*)ob;
  *(uint4*)(dst + 8) = *(uint4*)(ob + 8);
}

// -------- fallback: single-pass attention (R3), used when ws too small --------
__global__ __launch_bounds__(256) void k_attn_full(const u16* __restrict__ qb,
                                                   const u16* __restrict__ kb,
                                                   const u16* __restrict__ vb,
                                                   u16* __restrict__ ctx) {
  __shared__ __align__(16) u16 Kl[64 * 64];
  __shared__ __align__(16) u16 Vt[64 * 64];
  __shared__ __align__(16) u16 Pl[4 * 16 * 64];
  int qt = (int)gridDim.y - 1 - (int)blockIdx.y;
  int bh = blockIdx.x;
  int b = bh / HH, h = bh % HH;
  int t = threadIdx.x, w = t >> 6, lane = t & 63;
  int l15 = lane & 15, l4 = lane >> 4;
  size_t rowbase = (size_t)b * SS;
  int hcol = h * 64;
  int qrow = qt * 64 + w * 16 + l15;
  const u16* qptr = qb + (rowbase + qrow) * DD + hcol;
  bf16x8 qf0 = *(const bf16x8*)(qptr + l4 * 8);
  bf16x8 qf1 = *(const bf16x8*)(qptr + 32 + l4 * 8);
  float m_r[4], l_r[4];
  f32x4 o[4];
#pragma unroll
  for (int r = 0; r < 4; r++) { m_r[r] = -3e38f; l_r[r] = 0.f; }
#pragma unroll
  for (int nd = 0; nd < 4; nd++) o[nd] = (f32x4){0.f, 0.f, 0.f, 0.f};
  char* Kb = (char*)Kl;
  char* Vb = (char*)Vt;
  char* Pb = (char*)(Pl + w * 16 * 64);
  const u16* kbase = kb + rowbase * DD + hcol;
  const u16* vbase = vb + rowbase * DD + hcol;
  int jj = lane, dblk = w * 8;
  const f32x4 z4 = {0.f, 0.f, 0.f, 0.f};
  uint4 kr[2], vr[2];
#pragma unroll
  for (int rep = 0; rep < 2; rep++) {
    int d8 = dblk + rep * 32;
    kr[rep] = *(const uint4*)(kbase + (size_t)jj * DD + d8);
    vr[rep] = *(const uint4*)(vbase + (size_t)jj * DD + d8);
  }
  for (int kt = 0; kt <= qt; kt++) {
#pragma unroll
    for (int rep = 0; rep < 2; rep++) {
      int d8 = dblk + rep * 32;
      *(uint4*)(Kb + ((jj * 128 + d8 * 2) ^ ((jj & 7) << 4))) = kr[rep];
      u16 el[8];
      *(uint4*)el = vr[rep];
#pragma unroll
      for (int ii = 0; ii < 8; ii++) {
        int d = d8 + ii;
        *(u16*)(Vb + ((d * 128 + jj * 2) ^ ((d & 7) << 4))) = el[ii];
      }
    }
    __syncthreads();
    if (kt < qt) {
#pragma unroll
      for (int rep = 0; rep < 2; rep++) {
        int row = (kt + 1) * 64 + jj;
        int d8 = dblk + rep * 32;
        kr[rep] = *(const uint4*)(kbase + (size_t)row * DD + d8);
        vr[rep] = *(const uint4*)(vbase + (size_t)row * DD + d8);
      }
    }
    f32x4 sacc[4];
#pragma unroll
    for (int nb = 0; nb < 4; nb++) {
      int row = nb * 16 + l15;
      bf16x8 kf0 = *(const bf16x8*)(Kb + ((row * 128 + l4 * 16) ^ ((row & 7) << 4)));
      bf16x8 kf1 = *(const bf16x8*)(Kb + ((row * 128 + 64 + l4 * 16) ^ ((row & 7) << 4)));
      sacc[nb] = MFMA(qf0, kf0, z4);
      sacc[nb] = MFMA(qf1, kf1, sacc[nb]);
    }
    float s[4][4];
#pragma unroll
    for (int nb = 0; nb < 4; nb++)
#pragma unroll
      for (int r = 0; r < 4; r++) s[nb][r] = sacc[nb][r] * 0.125f;
    if (kt == qt) {
#pragma unroll
      for (int nb = 0; nb < 4; nb++) {
        int jg = nb * 16 + l15;
#pragma unroll
        for (int r = 0; r < 4; r++) {
          int qg = w * 16 + l4 * 4 + r;
          if (jg > qg) s[nb][r] = -1e30f;
        }
      }
    }
    float alpha[4];
#pragma unroll
    for (int r = 0; r < 4; r++) {
      float mx = fmaxf(fmaxf(s[0][r], s[1][r]), fmaxf(s[2][r], s[3][r]));
      mx = fmaxf(mx, __shfl_xor(mx, 1, 64));
      mx = fmaxf(mx, __shfl_xor(mx, 2, 64));
      mx = fmaxf(mx, __shfl_xor(mx, 4, 64));
      mx = fmaxf(mx, __shfl_xor(mx, 8, 64));
      float mn = fmaxf(m_r[r], mx);
      alpha[r] = __expf(m_r[r] - mn);
      m_r[r] = mn;
      float rs = 0.f;
#pragma unroll
      for (int nb = 0; nb < 4; nb++) {
        float p = __expf(s[nb][r] - mn);
        s[nb][r] = p;
        rs += p;
      }
      rs += __shfl_xor(rs, 1, 64);
      rs += __shfl_xor(rs, 2, 64);
      rs += __shfl_xor(rs, 4, 64);
      rs += __shfl_xor(rs, 8, 64);
      l_r[r] = l_r[r] * alpha[r] + rs;
    }
#pragma unroll
    for (int nb = 0; nb < 4; nb++)
#pragma unroll
      for (int r = 0; r < 4; r++) {
        int q = l4 * 4 + r;
        *(u16*)(Pb + ((q * 128 + (nb * 16 + l15) * 2) ^ ((q & 7) << 4))) =
            f2bf(s[nb][r]);
      }
#pragma unroll
    for (int nd = 0; nd < 4; nd++)
#pragma unroll
      for (int r = 0; r < 4; r++) o[nd][r] *= alpha[r];
    asm volatile("s_waitcnt lgkmcnt(0)" ::: "memory");
    bf16x8 pa0 = *(const bf16x8*)(Pb + ((l15 * 128 + l4 * 16) ^ ((l15 & 7) << 4)));
    bf16x8 pa1 = *(const bf16x8*)(Pb + ((l15 * 128 + 64 + l4 * 16) ^ ((l15 & 7) << 4)));
#pragma unroll
    for (int nd = 0; nd < 4; nd++) {
      int row = nd * 16 + l15;
      bf16x8 vf0 = *(const bf16x8*)(Vb + ((row * 128 + l4 * 16) ^ ((row & 7) << 4)));
      bf16x8 vf1 = *(const bf16x8*)(Vb + ((row * 128 + 64 + l4 * 16) ^ ((row & 7) << 4)));
      o[nd] = MFMA(pa0, vf0, o[nd]);
      o[nd] = MFMA(pa1, vf1, o[nd]);
    }
    __syncthreads();
  }
  size_t orow = rowbase + (size_t)qt * 64 + w * 16 + l4 * 4;
#pragma unroll
  for (int nd = 0; nd < 4; nd++)
#pragma unroll
    for (int r = 0; r < 4; r++) {
      float vv = o[nd][r] / l_r[r];
      ctx[(orow + r) * DD + hcol + nd * 16 + l15] = f2bf(vv);
    }
}

extern "C" void kernel_launch(void* const* d_in, const int* in_sizes, int n_in,
                              void* d_out, int out_size, void* d_ws, size_t ws_size,
                              hipStream_t stream) {
  const float* x  = (const float*)d_in[0];
  // d_in[1] = mask (causal, hard-coded)
  const float* Wq = (const float*)d_in[2];
  const float* bq = (const float*)d_in[3];
  const float* Wk = (const float*)d_in[4];
  const float* bk = (const float*)d_in[5];
  const float* Wv = (const float*)d_in[6];
  const float* bv = (const float*)d_in[7];
  const float* Wo = (const float*)d_in[8];
  const float* bo = (const float*)d_in[9];
  float* out = (float*)d_out;

  char* ws = (char*)d_ws;
  const size_t XN = (size_t)MROWS * DD;  // 3,145,728
  const size_t WN = (size_t)DD * DD;     // 589,824
  u16* xb  = (u16*)ws;                                 // XN
  u16* Wt  = (u16*)(ws + XN * 2);                      // 4*WN
  u16* qkv = (u16*)(ws + XN * 2 + WN * 8);             // 3*XN
  u16* ctx = (u16*)(ws + XN * 2 + WN * 8 + XN * 6);    // XN
  const size_t base = XN * 2 + WN * 8 + XN * 6 + XN * 2;  // 36,175,872
  const size_t NCHUNK = 24 * NSLOT;  // 1920
  u16*   PO = (u16*)(ws + base);                        // 1920*4096 u16
  float* PM = (float*)(ws + base + NCHUNK * 4096 * 2);  // 1920*64 f32
  float* PL = PM + NCHUNK * 64;
  const size_t need = base + NCHUNK * 4096 * 2 + 2 * NCHUNK * 64 * 4;

  k_convert<<<dim3((int)(XN / 1024)), 256, 0, stream>>>(x, xb, (int)XN);
  k_transpose_w<<<dim3(24, 24, 4), 256, 0, stream>>>(Wq, Wk, Wv, Wo, Wt);
  k_gemm_qkv<<<dim3(32, 6, 3), 256, 0, stream>>>(xb, Wt, bq, bk, bv, qkv);
  if (ws_size >= need) {
    k_attn_split<<<dim3(24, NSLOT), 256, 0, stream>>>(qkv, qkv + XN, qkv + 2 * XN,
                                                      PO, PM, PL);
    k_combine<<<dim3(24, 32), 256, 0, stream>>>(PO, PM, PL, ctx);
  } else {
    k_attn_full<<<dim3(24, 32), 256, 0, stream>>>(qkv, qkv + XN, qkv + 2 * XN, ctx);
  }
  k_gemm_out<<<dim3(32, 6), 256, 0, stream>>>(ctx, Wt + 3 * WN, bo, out);
}